// Round 9
// baseline (164.923 us; speedup 1.0000x reference)
//
#include <hip/hip_runtime.h>
#include <utility>

#define BB 16
#define TT 2048
#define DD 768
#define HH 96

typedef __attribute__((ext_vector_type(8))) short bf16x8;
typedef __attribute__((ext_vector_type(4))) short bf16x4;
typedef __attribute__((ext_vector_type(4))) float f32x4;

static __device__ __forceinline__ unsigned short f2bf(float f) {
  unsigned u = __builtin_bit_cast(unsigned, f);
  u = (u + 0x7fffu + ((u >> 16) & 1u)) >> 16;   // round-to-nearest-even
  return (unsigned short)u;
}

// ---------------- W convert: Wt[w][n][k] bf16, w order = {q,k,v} ----------------
__global__ void wconv(const float* __restrict__ Wk, const float* __restrict__ Wq,
                      const float* __restrict__ Wv, unsigned short* __restrict__ Wt) {
  int idx = blockIdx.x * 256 + threadIdx.x;
  if (idx >= 3 * HH * DD) return;
  int w = idx / (HH * DD);
  int rem = idx - w * (HH * DD);
  int n = rem / DD;
  int k = rem - n * DD;
  const float* W = (w == 0) ? Wq : (w == 1) ? Wk : Wv;
  Wt[idx] = f2bf(W[k * HH + n]);
}

// ---------------- QKV projection (unchanged from r8: coalesced glds pipeline) ----------------
__global__ __launch_bounds__(384, 3) void qkv_proj(
    const float* __restrict__ x, const unsigned short* __restrict__ Wt,
    unsigned short* __restrict__ Qb, unsigned short* __restrict__ Kb,
    unsigned short* __restrict__ Vt) {
  __shared__ float Xlds[2][64 * 32];             // 2 x 8 KB
  __shared__ unsigned short Wlds[2][288 * 32];   // 2 x 18 KB
  const int tid = threadIdx.x;
  const int lane = tid & 63;
  const int w = tid >> 6;
  const int g = lane >> 4;
  const int m = lane & 15;
  const int outsel = w % 3;
  const int rg = w / 3;
  const long r0 = (long)blockIdx.x * 64;
  const long rw = r0 + rg * 32;

  f32x4 acc[2][6];
#pragma unroll
  for (int u = 0; u < 2; ++u)
#pragma unroll
    for (int nf = 0; nf < 6; ++nf) { acc[u][nf][0] = 0.f; acc[u][nf][1] = 0.f; acc[u][nf][2] = 0.f; acc[u][nf][3] = 0.f; }

  auto stage = [&](int P, int t) {
#pragma unroll
    for (int i = w; i < 18; i += 6) {
      const unsigned short* src = Wt + (long)(i * 16 + (lane >> 2)) * DD + t * 32 + (lane & 3) * 8;
      __builtin_amdgcn_global_load_lds(
          (const __attribute__((address_space(1))) void*)src,
          (__attribute__((address_space(3))) void*)(&Wlds[P][i * 512]), 16, 0, 0);
    }
#pragma unroll
    for (int i = w; i < 8; i += 6) {
      const float* src = x + (r0 + i * 8 + (lane >> 3)) * DD + t * 32 + (lane & 7) * 4;
      __builtin_amdgcn_global_load_lds(
          (const __attribute__((address_space(1))) void*)src,
          (__attribute__((address_space(3))) void*)(&Xlds[P][i * 256]), 16, 0, 0);
    }
  };

  auto compute = [&](int P) {
    bf16x8 a[2];
#pragma unroll
    for (int u = 0; u < 2; ++u) {
      const int row = rg * 32 + u * 16 + m;
      f32x4 lo = *(const f32x4*)(&Xlds[P][row * 32 + g * 8]);
      f32x4 hi = *(const f32x4*)(&Xlds[P][row * 32 + g * 8 + 4]);
#pragma unroll
      for (int jj = 0; jj < 4; ++jj) { a[u][jj] = (short)f2bf(lo[jj]); a[u][4 + jj] = (short)f2bf(hi[jj]); }
    }
#pragma unroll
    for (int nf = 0; nf < 6; ++nf) {
      bf16x8 wf = *(const bf16x8*)(&Wlds[P][(outsel * 96 + nf * 16 + m) * 32 + g * 8]);
      acc[0][nf] = __builtin_amdgcn_mfma_f32_16x16x32_bf16(a[0], wf, acc[0][nf], 0, 0, 0);
      acc[1][nf] = __builtin_amdgcn_mfma_f32_16x16x32_bf16(a[1], wf, acc[1][nf], 0, 0, 0);
    }
  };

  auto phase = [&](int t, int drain) {
    if (drain) { asm volatile("s_waitcnt vmcnt(0)" ::: "memory"); }
    else if (w < 2) { asm volatile("s_waitcnt vmcnt(5)" ::: "memory"); }
    else { asm volatile("s_waitcnt vmcnt(4)" ::: "memory"); }
    __builtin_amdgcn_sched_barrier(0);
    __builtin_amdgcn_s_barrier();
    __builtin_amdgcn_sched_barrier(0);
    compute(t & 1);
    asm volatile("s_waitcnt lgkmcnt(0)" ::: "memory");
    __builtin_amdgcn_sched_barrier(0);
    __builtin_amdgcn_s_barrier();
    __builtin_amdgcn_sched_barrier(0);
  };

  stage(0, 0);
  stage(1, 1);
  __builtin_amdgcn_sched_barrier(0);
  for (int t = 0; t < 22; ++t) {
    phase(t, 0);
    stage(t & 1, t + 2);
    __builtin_amdgcn_sched_barrier(0);
  }
  phase(22, 0);
  phase(23, 1);

  unsigned short (*vst)[72] = (unsigned short (*)[72])(&Xlds[0][0]);
  if (outsel == 0) {
#pragma unroll
    for (int u = 0; u < 2; ++u)
#pragma unroll
      for (int nf = 0; nf < 6; ++nf)
#pragma unroll
        for (int r = 0; r < 4; ++r)
          Qb[(rw + u * 16 + 4 * g + r) * HH + nf * 16 + m] = f2bf(acc[u][nf][r]);
  } else if (outsel == 1) {
#pragma unroll
    for (int u = 0; u < 2; ++u)
#pragma unroll
      for (int nf = 0; nf < 6; ++nf)
#pragma unroll
        for (int r = 0; r < 4; ++r)
          Kb[(rw + u * 16 + 4 * g + r) * HH + nf * 16 + m] = f2bf(acc[u][nf][r]);
  } else {
#pragma unroll
    for (int u = 0; u < 2; ++u)
#pragma unroll
      for (int nf = 0; nf < 6; ++nf)
#pragma unroll
        for (int r = 0; r < 4; ++r)
          vst[nf * 16 + m][rg * 32 + u * 16 + 4 * g + r] = f2bf(acc[u][nf][r]);
  }
  __syncthreads();
  const int bidx = (int)(r0 >> 11);
  const int t0 = (int)(r0 & 2047);
#pragma unroll
  for (int jj = 0; jj < 2; ++jj) {
    int flat = tid + jj * 384;
    int h = flat >> 3;
    int t8 = (flat & 7) * 8;
    bf16x8 v = *(const bf16x8*)(&vst[h][t8]);
    *(bf16x8*)(Vt + ((long)(bidx * HH + h) * TT + t0 + t8)) = v;
  }
}

// ---------------- flash attention v3: 8 waves, 2-way KV-parity split ----------------
// 512 blocks x 512 thr. Waves w: parity p=w>>2 handles tiles t=2u+p; sub-wave
// ws=w&3 -> q = q0 + 4c + ws (waves w and w+4 share q-rows, merged at end).
// K per-parity LDS dbuf [64][104]; V direct from global (L2-resident). One
// barrier per tile-unit. Balanced mapping: CU's two blocks sum to 32 units;
// each XCD sees 2 batches (K/V L2-resident).
__global__ __launch_bounds__(512, 4) void attn(
    const unsigned short* __restrict__ Qb, const unsigned short* __restrict__ Kb,
    const unsigned short* __restrict__ Vt, float* __restrict__ out) {
  __shared__ unsigned short Klds[2][2][64 * 104];   // [parity][buf] 53.2 KB
  const int tid = threadIdx.x;
  const int lane = tid & 63;
  const int w = tid >> 6;
  const int p = w >> 2;                    // kv parity
  const int ws = w & 3;                    // q-interleave slot
  const int ltid = tid & 255;              // parity-local tid
  const int g = lane >> 4;
  const int c = lane & 15;

  // balanced + XCD-pinned mapping
  const int blk = (int)blockIdx.x;
  const int half = blk >> 8;
  const int i0 = blk & 255;
  const int xcd = i0 & 7;
  const int j0 = i0 >> 3;                  // 0..31
  const int b = (xcd << 1) | half;
  const int qt = half ? j0 : 31 - j0;
  const int q0 = qt * 64;
  const int U = qt >> 1;                   // max parity-unit (for p=0)

  bf16x8 qf[3];
  {
    const unsigned short* qrow = Qb + ((long)b * TT + q0 + 4 * c + ws) * HH;
#pragma unroll
    for (int ks = 0; ks < 3; ++ks) qf[ks] = *(const bf16x8*)(qrow + ks * 32 + g * 8);
  }

  const unsigned short* Kbase = Kb + (long)b * TT * HH;
  const unsigned short* vrow = Vt + (long)b * HH * TT + (long)c * TT;  // lane's V row base (h = nf*16+c)

  f32x4 o[6];
#pragma unroll
  for (int nf = 0; nf < 6; ++nf) { o[nf][0] = 0.f; o[nf][1] = 0.f; o[nf][2] = 0.f; o[nf][3] = 0.f; }
  float m_run = -1e30f, l_run = 0.f;
  const float SCL = 0.10206207261596577f * 1.44269504088896f;  // HS^-0.5 * log2(e)

  bf16x8 kreg[3];                          // single-deep K staging (3 granules/lane)

  auto issue = [&](int u) {                // global -> reg, tile t = 2u+p
    const int t = 2 * u + p;
    if (t <= qt) {
      const unsigned short* ksrc = Kbase + (long)t * 64 * HH;
#pragma unroll
      for (int i = 0; i < 3; ++i) kreg[i] = *(const bf16x8*)(ksrc + (ltid + i * 256) * 8);
    }
  };
  auto lwrite = [&](int B, int u) {        // reg -> LDS
    const int t = 2 * u + p;
    if (t <= qt) {
#pragma unroll
      for (int i = 0; i < 3; ++i) {
        int j = ltid + i * 256;
        int row = j / 12, gs = j - row * 12;
        *(bf16x8*)(&Klds[p][B][row * 104 + gs * 8]) = kreg[i];
      }
    }
  };
  auto bar = [&]() {
    asm volatile("s_waitcnt lgkmcnt(0)" ::: "memory");
    __builtin_amdgcn_s_barrier();
    __builtin_amdgcn_sched_barrier(0);
  };
  auto compute = [&](int B, int u) {
    const int t = 2 * u + p;
    if (t > qt) return;
    const int kv0 = t * 64;
    // V kf=0 loads (consumed after softmax)
    bf16x4 vlo0[6], vhi0[6];
#pragma unroll
    for (int nf = 0; nf < 6; ++nf) {
      const unsigned short* vr = vrow + (long)nf * 16 * TT + kv0 + 4 * g;
      vlo0[nf] = *(const bf16x4*)(vr);
      vhi0[nf] = *(const bf16x4*)(vr + 16);
    }
    // QK^T (swapped): S^T rows = kv, cols = q
    f32x4 s[4];
#pragma unroll
    for (int mf = 0; mf < 4; ++mf) { s[mf][0] = 0.f; s[mf][1] = 0.f; s[mf][2] = 0.f; s[mf][3] = 0.f; }
    __builtin_amdgcn_s_setprio(1);
#pragma unroll
    for (int ks = 0; ks < 3; ++ks) {
      bf16x8 kb_[4];
#pragma unroll
      for (int mf = 0; mf < 4; ++mf)
        kb_[mf] = *(const bf16x8*)(&Klds[p][B][(mf * 16 + c) * 104 + ks * 32 + g * 8]);
#pragma unroll
      for (int mf = 0; mf < 4; ++mf)
        s[mf] = __builtin_amdgcn_mfma_f32_16x16x32_bf16(kb_[mf], qf[ks], s[mf], 0, 0, 0);
    }
    __builtin_amdgcn_s_setprio(0);
    // V kf=1 loads (hide under softmax)
    bf16x4 vlo1[6], vhi1[6];
#pragma unroll
    for (int nf = 0; nf < 6; ++nf) {
      const unsigned short* vr = vrow + (long)nf * 16 * TT + kv0 + 32 + 4 * g;
      vlo1[nf] = *(const bf16x4*)(vr);
      vhi1[nf] = *(const bf16x4*)(vr + 16);
    }
    // softmax (log2 domain)
    const int qcol = q0 + 4 * c + ws;
    const bool diag = (t == qt);
    float smax = -1e30f;
#pragma unroll
    for (int mf = 0; mf < 4; ++mf)
#pragma unroll
      for (int r = 0; r < 4; ++r) {
        float v = s[mf][r] * SCL;
        if (diag && (kv0 + mf * 16 + 4 * g + r) > qcol) v = -1e30f;
        s[mf][r] = v;
        smax = fmaxf(smax, v);
      }
    smax = fmaxf(smax, __shfl_xor(smax, 16));
    smax = fmaxf(smax, __shfl_xor(smax, 32));
    const float m_new = fmaxf(m_run, smax);
    const float corr = __builtin_amdgcn_exp2f(m_run - m_new);
    float rsum = 0.f;
    unsigned short pb[4][4];
#pragma unroll
    for (int mf = 0; mf < 4; ++mf)
#pragma unroll
      for (int r = 0; r < 4; ++r) {
        float pv = __builtin_amdgcn_exp2f(s[mf][r] - m_new);
        rsum += pv;
        pb[mf][r] = f2bf(pv);
      }
    rsum += __shfl_xor(rsum, 16);
    rsum += __shfl_xor(rsum, 32);
    l_run = l_run * corr + rsum;
    m_run = m_new;
#pragma unroll
    for (int r = 0; r < 4; ++r) {
      float cr = __shfl(corr, 4 * g + r);
#pragma unroll
      for (int nf = 0; nf < 6; ++nf) o[nf][r] *= cr;
    }
    // PV: A-slot (g,i) -> kv = 4g + (i&3) + 16*(2kf + (i>>2)); V loaded with same map
    __builtin_amdgcn_s_setprio(1);
#pragma unroll
    for (int kf = 0; kf < 2; ++kf) {
      bf16x8 a;
#pragma unroll
      for (int i = 0; i < 8; ++i) a[i] = (short)pb[2 * kf + (i >> 2)][i & 3];
#pragma unroll
      for (int nf = 0; nf < 6; ++nf) {
        bf16x4 lo = kf ? vlo1[nf] : vlo0[nf];
        bf16x4 hi = kf ? vhi1[nf] : vhi0[nf];
        bf16x8 vf = __builtin_shufflevector(lo, hi, 0, 1, 2, 3, 4, 5, 6, 7);
        o[nf] = __builtin_amdgcn_mfma_f32_16x16x32_bf16(a, vf, o[nf], 0, 0, 0);
      }
    }
    __builtin_amdgcn_s_setprio(0);
  };

  // prologue: stage unit 0
  issue(0);
  lwrite(0, 0);
  bar();
  // main loop: one tile-unit per iteration, ONE barrier per iteration
  for (int u = 0; u <= U; ++u) {
    issue(u + 1);
    compute(u & 1, u);
    lwrite((u + 1) & 1, u + 1);
    bar();
  }

  // -------- merge parity partials (waves w and w+4 share q-rows) --------
  float* sm = (float*)&Klds[0][0][0];      // 26.6 KB scratch (loop done)
  __syncthreads();
  if (p == 1) {
    const int base = (ws * 64 + lane) * 26;
    sm[base] = m_run;
    sm[base + 1] = l_run;
#pragma unroll
    for (int nf = 0; nf < 6; ++nf)
#pragma unroll
      for (int r = 0; r < 4; ++r) sm[base + 2 + nf * 4 + r] = o[nf][r];
  }
  __syncthreads();
  if (p == 0) {
    const int base = (ws * 64 + lane) * 26;
    const float mj = sm[base], lj = sm[base + 1];
    const float mn = fmaxf(m_run, mj);
    const float c0 = __builtin_amdgcn_exp2f(m_run - mn);
    const float cj = __builtin_amdgcn_exp2f(mj - mn);
    const float l_f = l_run * c0 + lj * cj;
    const float inv = 1.0f / l_f;
#pragma unroll
    for (int r = 0; r < 4; ++r) {
      const float c0r = __shfl(c0, 4 * g + r);
      const float cjr = __shfl(cj, 4 * g + r);
      const float ivr = __shfl(inv, 4 * g + r);
      long orow = ((long)b * TT + q0 + 16 * g + 4 * r + ws) * HH;
#pragma unroll
      for (int nf = 0; nf < 6; ++nf) {
        float oj = sm[base + 2 + nf * 4 + r];
        out[orow + nf * 16 + c] = (o[nf][r] * c0r + oj * cjr) * ivr;
      }
    }
  }
}

extern "C" void kernel_launch(void* const* d_in, const int* in_sizes, int n_in,
                              void* d_out, int out_size, void* d_ws, size_t ws_size,
                              hipStream_t stream) {
  const float* x  = (const float*)d_in[0];
  const float* Wk = (const float*)d_in[1];
  const float* Wq = (const float*)d_in[2];
  const float* Wv = (const float*)d_in[3];
  float* out = (float*)d_out;

  unsigned short* Wt = (unsigned short*)d_ws;        // 3*96*768 bf16 = 442 KB
  unsigned short* Qb = Wt + 3 * HH * DD;             // [B*T][96] bf16
  unsigned short* Kb = Qb + (long)BB * TT * HH;      // [B*T][96] bf16
  unsigned short* Vt = Kb + (long)BB * TT * HH;      // [B][96][T] bf16 (transposed)

  wconv<<<dim3((3 * HH * DD + 255) / 256), dim3(256), 0, stream>>>(Wk, Wq, Wv, Wt);
  qkv_proj<<<dim3(BB * TT / 64), dim3(384), 0, stream>>>(x, Wt, Qb, Kb, Vt);
  attn<<<dim3(512), dim3(512), 0, stream>>>(Qb, Kb, Vt, out);
}

// Round 10
// 85.951 us; speedup vs baseline: 1.9188x; 1.9188x over previous
//
#include <hip/hip_runtime.h>
#include <utility>

#define BB 16
#define TT 2048
#define DD 768
#define HH 96

typedef __attribute__((ext_vector_type(8))) short bf16x8;
typedef __attribute__((ext_vector_type(4))) short bf16x4;
typedef __attribute__((ext_vector_type(4))) float f32x4;

static __device__ __forceinline__ unsigned short f2bf(float f) {
  unsigned u = __builtin_bit_cast(unsigned, f);
  u = (u + 0x7fffu + ((u >> 16) & 1u)) >> 16;   // round-to-nearest-even
  return (unsigned short)u;
}

// ---------------- W convert: Wt[w][n][k] bf16, w order = {q,k,v} ----------------
__global__ void wconv(const float* __restrict__ Wk, const float* __restrict__ Wq,
                      const float* __restrict__ Wv, unsigned short* __restrict__ Wt) {
  int idx = blockIdx.x * 256 + threadIdx.x;
  if (idx >= 3 * HH * DD) return;
  int w = idx / (HH * DD);
  int rem = idx - w * (HH * DD);
  int n = rem / DD;
  int k = rem - n * DD;
  const float* W = (w == 0) ? Wq : (w == 1) ? Wk : Wv;
  Wt[idx] = f2bf(W[k * HH + n]);
}

// ---------------- QKV projection (unchanged from r8: coalesced glds pipeline) ----------------
__global__ __launch_bounds__(384, 3) void qkv_proj(
    const float* __restrict__ x, const unsigned short* __restrict__ Wt,
    unsigned short* __restrict__ Qb, unsigned short* __restrict__ Kb,
    unsigned short* __restrict__ Vt) {
  __shared__ float Xlds[2][64 * 32];             // 2 x 8 KB
  __shared__ unsigned short Wlds[2][288 * 32];   // 2 x 18 KB
  const int tid = threadIdx.x;
  const int lane = tid & 63;
  const int w = tid >> 6;
  const int g = lane >> 4;
  const int m = lane & 15;
  const int outsel = w % 3;
  const int rg = w / 3;
  const long r0 = (long)blockIdx.x * 64;
  const long rw = r0 + rg * 32;

  f32x4 acc[2][6];
#pragma unroll
  for (int u = 0; u < 2; ++u)
#pragma unroll
    for (int nf = 0; nf < 6; ++nf) { acc[u][nf][0] = 0.f; acc[u][nf][1] = 0.f; acc[u][nf][2] = 0.f; acc[u][nf][3] = 0.f; }

  auto stage = [&](int P, int t) {
#pragma unroll
    for (int i = w; i < 18; i += 6) {
      const unsigned short* src = Wt + (long)(i * 16 + (lane >> 2)) * DD + t * 32 + (lane & 3) * 8;
      __builtin_amdgcn_global_load_lds(
          (const __attribute__((address_space(1))) void*)src,
          (__attribute__((address_space(3))) void*)(&Wlds[P][i * 512]), 16, 0, 0);
    }
#pragma unroll
    for (int i = w; i < 8; i += 6) {
      const float* src = x + (r0 + i * 8 + (lane >> 3)) * DD + t * 32 + (lane & 7) * 4;
      __builtin_amdgcn_global_load_lds(
          (const __attribute__((address_space(1))) void*)src,
          (__attribute__((address_space(3))) void*)(&Xlds[P][i * 256]), 16, 0, 0);
    }
  };

  auto compute = [&](int P) {
    bf16x8 a[2];
#pragma unroll
    for (int u = 0; u < 2; ++u) {
      const int row = rg * 32 + u * 16 + m;
      f32x4 lo = *(const f32x4*)(&Xlds[P][row * 32 + g * 8]);
      f32x4 hi = *(const f32x4*)(&Xlds[P][row * 32 + g * 8 + 4]);
#pragma unroll
      for (int jj = 0; jj < 4; ++jj) { a[u][jj] = (short)f2bf(lo[jj]); a[u][4 + jj] = (short)f2bf(hi[jj]); }
    }
#pragma unroll
    for (int nf = 0; nf < 6; ++nf) {
      bf16x8 wf = *(const bf16x8*)(&Wlds[P][(outsel * 96 + nf * 16 + m) * 32 + g * 8]);
      acc[0][nf] = __builtin_amdgcn_mfma_f32_16x16x32_bf16(a[0], wf, acc[0][nf], 0, 0, 0);
      acc[1][nf] = __builtin_amdgcn_mfma_f32_16x16x32_bf16(a[1], wf, acc[1][nf], 0, 0, 0);
    }
  };

  auto phase = [&](int t, int drain) {
    if (drain) { asm volatile("s_waitcnt vmcnt(0)" ::: "memory"); }
    else if (w < 2) { asm volatile("s_waitcnt vmcnt(5)" ::: "memory"); }
    else { asm volatile("s_waitcnt vmcnt(4)" ::: "memory"); }
    __builtin_amdgcn_sched_barrier(0);
    __builtin_amdgcn_s_barrier();
    __builtin_amdgcn_sched_barrier(0);
    compute(t & 1);
    asm volatile("s_waitcnt lgkmcnt(0)" ::: "memory");
    __builtin_amdgcn_sched_barrier(0);
    __builtin_amdgcn_s_barrier();
    __builtin_amdgcn_sched_barrier(0);
  };

  stage(0, 0);
  stage(1, 1);
  __builtin_amdgcn_sched_barrier(0);
  for (int t = 0; t < 22; ++t) {
    phase(t, 0);
    stage(t & 1, t + 2);
    __builtin_amdgcn_sched_barrier(0);
  }
  phase(22, 0);
  phase(23, 1);

  unsigned short (*vst)[72] = (unsigned short (*)[72])(&Xlds[0][0]);
  if (outsel == 0) {
#pragma unroll
    for (int u = 0; u < 2; ++u)
#pragma unroll
      for (int nf = 0; nf < 6; ++nf)
#pragma unroll
        for (int r = 0; r < 4; ++r)
          Qb[(rw + u * 16 + 4 * g + r) * HH + nf * 16 + m] = f2bf(acc[u][nf][r]);
  } else if (outsel == 1) {
#pragma unroll
    for (int u = 0; u < 2; ++u)
#pragma unroll
      for (int nf = 0; nf < 6; ++nf)
#pragma unroll
        for (int r = 0; r < 4; ++r)
          Kb[(rw + u * 16 + 4 * g + r) * HH + nf * 16 + m] = f2bf(acc[u][nf][r]);
  } else {
#pragma unroll
    for (int u = 0; u < 2; ++u)
#pragma unroll
      for (int nf = 0; nf < 6; ++nf)
#pragma unroll
        for (int r = 0; r < 4; ++r)
          vst[nf * 16 + m][rg * 32 + u * 16 + 4 * g + r] = f2bf(acc[u][nf][r]);
  }
  __syncthreads();
  const int bidx = (int)(r0 >> 11);
  const int t0 = (int)(r0 & 2047);
#pragma unroll
  for (int jj = 0; jj < 2; ++jj) {
    int flat = tid + jj * 384;
    int h = flat >> 3;
    int t8 = (flat & 7) * 8;
    bf16x8 v = *(const bf16x8*)(&vst[h][t8]);
    *(bf16x8*)(Vt + ((long)(bidx * HH + h) * TT + t0 + t8)) = v;
  }
}

// ---------------- flash attention: r8 per-wave structure + block-level KV-parity split ----------------
// 1024 blocks x 256 thr (4 waves). blk -> xcd=blk&7 (batch pinned to XCD), par,
// j2 -> (b, qt) with qt descending (heavy-first). Block processes tiles
// t = par, par+2, ... <= qt. par0 writes unnormalized O to out + stats; par1 to
// ws. attn_merge combines. LDS 52 KB -> 3 blocks/CU.
__global__ __launch_bounds__(256, 3) void attn(
    const unsigned short* __restrict__ Qb, const unsigned short* __restrict__ Kb,
    const unsigned short* __restrict__ Vt, float* __restrict__ out,
    float* __restrict__ Part1, float* __restrict__ St0, float* __restrict__ St1) {
  __shared__ unsigned short Klds[2][64 * 100];   // 64 rows x (96 + 4 pad) = 25 KB
  __shared__ unsigned short Vlds[2][96 * 72];    // 96 rows x (64 + 8 pad) = 27 KB
  const int tid = threadIdx.x;
  const int lane = tid & 63;
  const int w = tid >> 6;
  const int g = lane >> 4;
  const int c = lane & 15;

  const int blk = (int)blockIdx.x;
  const int xcd = blk & 7;
  const int rest = blk >> 3;               // 0..127
  const int par = rest & 1;
  const int j2 = rest >> 1;                // 0..63
  const int b = (xcd << 1) | (j2 & 1);
  const int qt = 31 - (j2 >> 1);           // heavy-first
  const int pair = (j2 << 3) | xcd;        // 0..511, merge-kernel consistent
  const int q0 = qt * 64;
  const int NU = (qt >= par) ? ((qt - par) >> 1) + 1 : 0;

  bf16x8 qf[3];
  {
    const unsigned short* qrow = Qb + ((long)b * TT + q0 + 4 * c + w) * HH;
#pragma unroll
    for (int ks = 0; ks < 3; ++ks) qf[ks] = *(const bf16x8*)(qrow + ks * 32 + g * 8);
  }

  const unsigned short* Kbase = Kb + (long)b * TT * HH;
  const unsigned short* Vbase = Vt + (long)b * HH * TT;

  f32x4 o[6];
#pragma unroll
  for (int nf = 0; nf < 6; ++nf) { o[nf][0] = 0.f; o[nf][1] = 0.f; o[nf][2] = 0.f; o[nf][3] = 0.f; }
  float m_run = -1e30f, l_run = 0.f;
  const float SCL = 0.10206207261596577f * 1.44269504088896f;  // HS^-0.5 * log2(e)

  bf16x8 kreg[2][3], vreg[2][3];

  auto issue = [&](auto PC, int u) {       // global -> reg, tile t = par + 2u
    constexpr int P = decltype(PC)::value;
    if (u < NU) {
      const int t = par + 2 * u;
      const unsigned short* ksrc = Kbase + (long)t * 64 * HH;
#pragma unroll
      for (int i = 0; i < 3; ++i) kreg[P][i] = *(const bf16x8*)(ksrc + (tid + i * 256) * 8);
#pragma unroll
      for (int i = 0; i < 3; ++i) {
        int j = tid + i * 256;
        vreg[P][i] = *(const bf16x8*)(Vbase + (long)(j >> 3) * TT + t * 64 + (j & 7) * 8);
      }
    }
  };
  auto lwrite = [&](auto PC, int u) {      // reg -> LDS
    constexpr int P = decltype(PC)::value;
    if (u < NU) {
#pragma unroll
      for (int i = 0; i < 3; ++i) {
        int j = tid + i * 256;
        int row = j / 12, gs = j - row * 12;
        *(bf16x8*)(&Klds[P][row * 100 + gs * 8]) = kreg[P][i];
      }
#pragma unroll
      for (int i = 0; i < 3; ++i) {
        int j = tid + i * 256;
        *(bf16x8*)(&Vlds[P][(j >> 3) * 72 + (j & 7) * 8]) = vreg[P][i];
      }
    }
  };
  auto bar = [&]() {
    asm volatile("s_waitcnt lgkmcnt(0)" ::: "memory");
    __builtin_amdgcn_s_barrier();
    __builtin_amdgcn_sched_barrier(0);
  };
  auto compute = [&](auto PC, int u) {
    constexpr int P = decltype(PC)::value;
    if (u >= NU) return;
    const int t = par + 2 * u;
    const int kv0 = t * 64;
    f32x4 s[4];
#pragma unroll
    for (int mf = 0; mf < 4; ++mf) { s[mf][0] = 0.f; s[mf][1] = 0.f; s[mf][2] = 0.f; s[mf][3] = 0.f; }
    __builtin_amdgcn_s_setprio(1);
#pragma unroll
    for (int ks = 0; ks < 3; ++ks) {
      bf16x8 kb_[4];
#pragma unroll
      for (int mf = 0; mf < 4; ++mf)
        kb_[mf] = *(const bf16x8*)(&Klds[P][(mf * 16 + c) * 100 + ks * 32 + g * 8]);
#pragma unroll
      for (int mf = 0; mf < 4; ++mf)
        s[mf] = __builtin_amdgcn_mfma_f32_16x16x32_bf16(kb_[mf], qf[ks], s[mf], 0, 0, 0);
    }
    __builtin_amdgcn_s_setprio(0);
    const int qcol = q0 + 4 * c + w;
    const bool diag = (t == qt);
    float smax = -1e30f;
#pragma unroll
    for (int mf = 0; mf < 4; ++mf)
#pragma unroll
      for (int r = 0; r < 4; ++r) {
        float v = s[mf][r] * SCL;
        if (diag && (kv0 + mf * 16 + 4 * g + r) > qcol) v = -1e30f;
        s[mf][r] = v;
        smax = fmaxf(smax, v);
      }
    smax = fmaxf(smax, __shfl_xor(smax, 16));
    smax = fmaxf(smax, __shfl_xor(smax, 32));
    const float m_new = fmaxf(m_run, smax);
    const float corr = __builtin_amdgcn_exp2f(m_run - m_new);
    float rsum = 0.f;
    unsigned short pb[4][4];
#pragma unroll
    for (int mf = 0; mf < 4; ++mf)
#pragma unroll
      for (int r = 0; r < 4; ++r) {
        float pv = __builtin_amdgcn_exp2f(s[mf][r] - m_new);
        rsum += pv;
        pb[mf][r] = f2bf(pv);
      }
    rsum += __shfl_xor(rsum, 16);
    rsum += __shfl_xor(rsum, 32);
    l_run = l_run * corr + rsum;
    m_run = m_new;
#pragma unroll
    for (int r = 0; r < 4; ++r) {
      float cr = __shfl(corr, 4 * g + r);
#pragma unroll
      for (int nf = 0; nf < 6; ++nf) o[nf][r] *= cr;
    }
    __builtin_amdgcn_s_setprio(1);
#pragma unroll
    for (int kf = 0; kf < 2; ++kf) {
      bf16x8 a;
#pragma unroll
      for (int i = 0; i < 8; ++i) a[i] = (short)pb[2 * kf + (i >> 2)][i & 3];
#pragma unroll
      for (int nf = 0; nf < 6; ++nf) {
        const unsigned short* vr = &Vlds[P][(nf * 16 + c) * 72 + kf * 32 + 4 * g];
        bf16x4 lo = *(const bf16x4*)(vr);
        bf16x4 hi = *(const bf16x4*)(vr + 16);
        bf16x8 vf = __builtin_shufflevector(lo, hi, 0, 1, 2, 3, 4, 5, 6, 7);
        o[nf] = __builtin_amdgcn_mfma_f32_16x16x32_bf16(a, vf, o[nf], 0, 0, 0);
      }
    }
    __builtin_amdgcn_s_setprio(0);
  };

  std::integral_constant<int, 0> P0;
  std::integral_constant<int, 1> P1;

  issue(P0, 0);
  issue(P1, 1);
  lwrite(P0, 0);
  bar();

  for (int u = 0; u < NU; u += 2) {
    issue(P0, u + 2);
    compute(P0, u);
    lwrite(P1, u + 1);
    bar();
    if (u + 1 < NU) {
      issue(P1, u + 3);
      compute(P1, u + 1);
      lwrite(P0, u + 2);
      bar();
    }
  }

  // -------- epilogue: write unnormalized partial + stats --------
  if (par == 0) {
#pragma unroll
    for (int r = 0; r < 4; ++r) {
      long orow = ((long)b * TT + q0 + 16 * g + 4 * r + w) * HH;
#pragma unroll
      for (int nf = 0; nf < 6; ++nf) out[orow + nf * 16 + c] = o[nf][r];
    }
    if (g == 0) {
      int sb = (pair << 6) + 4 * c + w;
      St0[sb * 2] = m_run;
      St0[sb * 2 + 1] = l_run;
    }
  } else {
#pragma unroll
    for (int r = 0; r < 4; ++r) {
      long prow = ((long)(pair << 6) + 16 * g + 4 * r + w) * HH;
#pragma unroll
      for (int nf = 0; nf < 6; ++nf) Part1[prow + nf * 16 + c] = o[nf][r];
    }
    if (g == 0) {
      int sb = (pair << 6) + 4 * c + w;
      St1[sb * 2] = m_run;
      St1[sb * 2 + 1] = l_run;
    }
  }
}

// ---------------- merge the two KV-parity partials ----------------
__global__ __launch_bounds__(256) void attn_merge(
    const float* __restrict__ Part1, const float* __restrict__ St0,
    const float* __restrict__ St1, float* __restrict__ out) {
  const int idx = (int)blockIdx.x * 256 + threadIdx.x;   // 131072
  const int row = idx >> 2;                // global q-row: b*2048 + q
  const int seg = idx & 3;                 // 24-float segment
  const int b = row >> 11;
  const int q = row & 2047;
  const int qt = q >> 6;
  const int qloc = q & 63;
  const int j2 = ((31 - qt) << 1) | (b & 1);
  const int pair = (j2 << 3) | (b >> 1);
  const int sb = (pair << 6) + qloc;
  const float m0 = St0[sb * 2], l0 = St0[sb * 2 + 1];
  const float m1 = St1[sb * 2], l1 = St1[sb * 2 + 1];
  const float mn = fmaxf(m0, m1);
  const float c0 = __builtin_amdgcn_exp2f(m0 - mn);
  const float c1 = __builtin_amdgcn_exp2f(m1 - mn);
  const float inv = 1.0f / (l0 * c0 + l1 * c1);
  float* o0 = out + (long)row * HH + seg * 24;
  const float* o1 = Part1 + (long)sb * HH + seg * 24;
#pragma unroll
  for (int j = 0; j < 6; ++j) {
    f32x4 a = *(const f32x4*)(o0 + j * 4);
    f32x4 bb = *(const f32x4*)(o1 + j * 4);
    f32x4 rr;
#pragma unroll
    for (int k = 0; k < 4; ++k) rr[k] = (a[k] * c0 + bb[k] * c1) * inv;
    *(f32x4*)(o0 + j * 4) = rr;
  }
}

extern "C" void kernel_launch(void* const* d_in, const int* in_sizes, int n_in,
                              void* d_out, int out_size, void* d_ws, size_t ws_size,
                              hipStream_t stream) {
  const float* x  = (const float*)d_in[0];
  const float* Wk = (const float*)d_in[1];
  const float* Wq = (const float*)d_in[2];
  const float* Wv = (const float*)d_in[3];
  float* out = (float*)d_out;

  unsigned short* Wt = (unsigned short*)d_ws;        // 3*96*768 bf16
  unsigned short* Qb = Wt + 3 * HH * DD;             // [B*T][96] bf16
  unsigned short* Kb = Qb + (long)BB * TT * HH;      // [B*T][96] bf16
  unsigned short* Vt = Kb + (long)BB * TT * HH;      // [B][96][T] bf16 (transposed)
  float* Part1 = (float*)(Vt + (long)BB * HH * TT);  // [512][64][96] f32 = 12.6 MB
  float* St0 = Part1 + (long)512 * 64 * HH;          // [512][64][2]
  float* St1 = St0 + 512 * 64 * 2;

  wconv<<<dim3((3 * HH * DD + 255) / 256), dim3(256), 0, stream>>>(Wk, Wq, Wv, Wt);
  qkv_proj<<<dim3(BB * TT / 64), dim3(384), 0, stream>>>(x, Wt, Qb, Kb, Vt);
  attn<<<dim3(1024), dim3(256), 0, stream>>>(Qb, Kb, Vt, out, Part1, St0, St1);
  attn_merge<<<dim3(512), dim3(256), 0, stream>>>(Part1, St0, St1, out);
}